// Round 1
// baseline (16175.343 us; speedup 1.0000x reference)
//
#include <hip/hip_runtime.h>

#define NN 50000
#define NE 800000
#define IN_DIM 16
#define H 32
#define EDGE_DIM 4
#define T_STEPS 4

// h0 = inputs @ W_emb  (no activation)
__global__ __launch_bounds__(256) void embed_kernel(const float* __restrict__ inputs,
                                                    const float* __restrict__ W_emb,
                                                    float* __restrict__ h) {
    __shared__ float W[IN_DIM * H];
    for (int i = threadIdx.x; i < IN_DIM * H; i += 256) W[i] = W_emb[i];
    __syncthreads();
    int idx = blockIdx.x * 256 + threadIdx.x;
    if (idx >= NN * H) return;
    int n = idx >> 5, j = idx & 31;
    const float* xr = inputs + n * IN_DIM;
    float acc = 0.f;
#pragma unroll
    for (int k = 0; k < IN_DIM; ++k) acc += xr[k] * W[k * H + j];
    h[idx] = acc;
}

// per-edge message m = relu([h[src]; ef] @ W_e), scatter-add to agg[dst]
__global__ __launch_bounds__(256) void edge_kernel(const float* __restrict__ h,
                                                   const float* __restrict__ e_feats,
                                                   const int* __restrict__ src,
                                                   const int* __restrict__ dst,
                                                   const float* __restrict__ We,
                                                   float* __restrict__ agg, int t) {
    __shared__ float W[36 * H];
    for (int i = threadIdx.x; i < 36 * H; i += 256) W[i] = We[i];
    __syncthreads();
    int e = blockIdx.x * 256 + threadIdx.x;
    if (e >= NE) return;
    int s = src[e], d = dst[e];

    float x[36];
    const float4* hrow = (const float4*)(h + s * H);
#pragma unroll
    for (int q = 0; q < 8; ++q) {
        float4 v = hrow[q];
        x[4 * q + 0] = v.x; x[4 * q + 1] = v.y; x[4 * q + 2] = v.z; x[4 * q + 3] = v.w;
    }
    // e_feats layout [E, EDGE_DIM, T]: (e,d,t) at e*16 + d*4 + t
#pragma unroll
    for (int dd = 0; dd < EDGE_DIM; ++dd) x[32 + dd] = e_feats[e * (EDGE_DIM * T_STEPS) + dd * T_STEPS + t];

    float acc[H];
#pragma unroll
    for (int j = 0; j < H; ++j) acc[j] = 0.f;
#pragma unroll
    for (int k = 0; k < 36; ++k) {
        float xk = x[k];
#pragma unroll
        for (int j = 0; j < H; j += 4) {
            float4 w = *(const float4*)&W[k * H + j];
            acc[j + 0] += xk * w.x;
            acc[j + 1] += xk * w.y;
            acc[j + 2] += xk * w.z;
            acc[j + 3] += xk * w.w;
        }
    }
    float* ar = agg + (long)d * H;
#pragma unroll
    for (int j = 0; j < H; ++j) atomicAdd(ar + j, fmaxf(acc[j], 0.f));
}

// h_new = relu([h; agg; rain] @ W_n); on last layer of timestep also r = h_new @ W_rain
__global__ __launch_bounds__(256) void node_kernel(const float* __restrict__ h,
                                                   const float* __restrict__ agg,
                                                   const float* __restrict__ rain0,
                                                   const float* __restrict__ Wn,
                                                   const float* __restrict__ Wrain,
                                                   float* __restrict__ hnew,
                                                   float* __restrict__ out, int t, int last) {
    __shared__ float W[65 * H];
    __shared__ float Wr[H];
    for (int i = threadIdx.x; i < 65 * H; i += 256) W[i] = Wn[i];
    if (threadIdx.x < H) Wr[threadIdx.x] = Wrain[threadIdx.x];
    __syncthreads();
    int n = blockIdx.x * 256 + threadIdx.x;
    if (n >= NN) return;

    float x[65];
    const float4* hr = (const float4*)(h + n * H);
    const float4* ar = (const float4*)(agg + n * H);
#pragma unroll
    for (int q = 0; q < 8; ++q) {
        float4 v = hr[q];
        x[4 * q + 0] = v.x; x[4 * q + 1] = v.y; x[4 * q + 2] = v.z; x[4 * q + 3] = v.w;
    }
#pragma unroll
    for (int q = 0; q < 8; ++q) {
        float4 v = ar[q];
        x[32 + 4 * q + 0] = v.x; x[32 + 4 * q + 1] = v.y; x[32 + 4 * q + 2] = v.z; x[32 + 4 * q + 3] = v.w;
    }
    x[64] = rain0[n * T_STEPS + t];

    float acc[H];
#pragma unroll
    for (int j = 0; j < H; ++j) acc[j] = 0.f;
#pragma unroll
    for (int k = 0; k < 65; ++k) {
        float xk = x[k];
#pragma unroll
        for (int j = 0; j < H; j += 4) {
            float4 w = *(const float4*)&W[k * H + j];
            acc[j + 0] += xk * w.x;
            acc[j + 1] += xk * w.y;
            acc[j + 2] += xk * w.z;
            acc[j + 3] += xk * w.w;
        }
    }

    float r = 0.f;
    float4* hw = (float4*)(hnew + n * H);
#pragma unroll
    for (int q = 0; q < 8; ++q) {
        float4 v;
        v.x = fmaxf(acc[4 * q + 0], 0.f);
        v.y = fmaxf(acc[4 * q + 1], 0.f);
        v.z = fmaxf(acc[4 * q + 2], 0.f);
        v.w = fmaxf(acc[4 * q + 3], 0.f);
        hw[q] = v;
        r += v.x * Wr[4 * q + 0] + v.y * Wr[4 * q + 1] + v.z * Wr[4 * q + 2] + v.w * Wr[4 * q + 3];
    }
    if (last) out[n * T_STEPS + t] = r;
}

extern "C" void kernel_launch(void* const* d_in, const int* in_sizes, int n_in,
                              void* d_out, int out_size, void* d_ws, size_t ws_size,
                              hipStream_t stream) {
    const float* inputs     = (const float*)d_in[0];
    const float* e_feats    = (const float*)d_in[1];
    const float* rain0      = (const float*)d_in[2];
    const float* W_emb      = (const float*)d_in[3];
    const float* W_edge_in  = (const float*)d_in[4];
    const float* W_node_in  = (const float*)d_in[5];
    const float* W_edge_out = (const float*)d_in[6];
    const float* W_node_out = (const float*)d_in[7];
    const float* W_rain     = (const float*)d_in[8];
    const int*   src        = (const int*)d_in[9];
    const int*   dst        = (const int*)d_in[10];
    float* out = (float*)d_out;

    float* h_a = (float*)d_ws;
    float* h_b = h_a + (size_t)NN * H;
    float* agg = h_b + (size_t)NN * H;

    embed_kernel<<<(NN * H + 255) / 256, 256, 0, stream>>>(inputs, W_emb, h_a);

    float* hc = h_a;
    float* hn = h_b;
    for (int t = 0; t < T_STEPS; ++t) {
        for (int s = 0; s < 3; ++s) {
            const float* We = (s < 2) ? (W_edge_in + (size_t)s * 36 * H) : W_edge_out;
            const float* Wn = (s < 2) ? (W_node_in + (size_t)s * 65 * H) : W_node_out;
            hipMemsetAsync(agg, 0, (size_t)NN * H * sizeof(float), stream);
            edge_kernel<<<(NE + 255) / 256, 256, 0, stream>>>(hc, e_feats, src, dst, We, agg, t);
            node_kernel<<<(NN + 255) / 256, 256, 0, stream>>>(hc, agg, rain0, Wn, W_rain, hn, out, t, (s == 2) ? 1 : 0);
            float* tmp = hc; hc = hn; hn = tmp;
        }
    }
}

// Round 2
// 1659.696 us; speedup vs baseline: 9.7460x; 9.7460x over previous
//
#include <hip/hip_runtime.h>

#define NN 50000
#define NE 800000
#define IN_DIM 16
#define H 32
#define EDGE_DIM 4
#define T_STEPS 4
#define HALF_E 400000

// ---------------- embedding: h0 = inputs @ W_emb ----------------
__global__ __launch_bounds__(256) void embed_kernel(const float* __restrict__ inputs,
                                                    const float* __restrict__ W_emb,
                                                    float* __restrict__ h) {
    __shared__ float W[IN_DIM * H];
    for (int i = threadIdx.x; i < IN_DIM * H; i += 256) W[i] = W_emb[i];
    __syncthreads();
    int idx = blockIdx.x * 256 + threadIdx.x;
    if (idx >= NN * H) return;
    int n = idx >> 5, j = idx & 31;
    const float* xr = inputs + n * IN_DIM;
    float acc = 0.f;
#pragma unroll
    for (int k = 0; k < IN_DIM; ++k) acc += xr[k] * W[k * H + j];
    h[idx] = acc;
}

// ---------------- CSR build ----------------
__global__ __launch_bounds__(256) void hist_kernel(const int* __restrict__ dst, int* __restrict__ deg) {
    int e = blockIdx.x * 256 + threadIdx.x;
    if (e < NE) atomicAdd(&deg[dst[e]], 1);
}

#define SCAN_CHUNK 49
__global__ __launch_bounds__(1024) void scan_kernel(const int* __restrict__ deg, int* __restrict__ row_ptr) {
    __shared__ int part[1024];
    int tid = threadIdx.x;
    int start = tid * SCAN_CHUNK;
    int s = 0;
    for (int i = 0; i < SCAN_CHUNK; ++i) {
        int idx = start + i;
        if (idx < NN) s += deg[idx];
    }
    part[tid] = s;
    __syncthreads();
    for (int off = 1; off < 1024; off <<= 1) {
        int v = (tid >= off) ? part[tid - off] : 0;
        __syncthreads();
        part[tid] += v;
        __syncthreads();
    }
    int run = (tid == 0) ? 0 : part[tid - 1];
    for (int i = 0; i < SCAN_CHUNK; ++i) {
        int idx = start + i;
        if (idx <= NN) row_ptr[idx] = run;
        if (idx < NN) run += deg[idx];
    }
}

__global__ __launch_bounds__(256) void scatter_kernel(const int* __restrict__ src, const int* __restrict__ dst,
                                                      const int* __restrict__ row_ptr, int* __restrict__ cnt,
                                                      int* __restrict__ src_sorted, int* __restrict__ eid_sorted) {
    int e = blockIdx.x * 256 + threadIdx.x;
    if (e >= NE) return;
    int d = dst[e];
    int pos = row_ptr[d] + atomicAdd(&cnt[d], 1);
    src_sorted[pos] = src[e];
    eid_sorted[pos] = e;
}

// ---------------- edge messages (no atomics): m[p] = relu([h[src_sorted[p]]; ef] @ W_e) ----------------
__global__ __launch_bounds__(256) void edge_sorted_kernel(const float* __restrict__ h,
                                                          const float* __restrict__ e_feats,
                                                          const int* __restrict__ src_sorted,
                                                          const int* __restrict__ eid_sorted,
                                                          const float* __restrict__ We,
                                                          float* __restrict__ m, int t) {
    __shared__ float W[36 * H];
    for (int i = threadIdx.x; i < 36 * H; i += 256) W[i] = We[i];
    __syncthreads();
    int p0 = blockIdx.x * 256 + threadIdx.x;
    if (p0 >= HALF_E) return;
    int p1 = p0 + HALF_E;

    int s0 = src_sorted[p0], s1 = src_sorted[p1];
    int e0 = eid_sorted[p0], e1 = eid_sorted[p1];

    float x0[36], x1[36];
    const float4* r0 = (const float4*)(h + (size_t)s0 * H);
    const float4* r1 = (const float4*)(h + (size_t)s1 * H);
#pragma unroll
    for (int q = 0; q < 8; ++q) {
        float4 v = r0[q];
        x0[4 * q + 0] = v.x; x0[4 * q + 1] = v.y; x0[4 * q + 2] = v.z; x0[4 * q + 3] = v.w;
    }
#pragma unroll
    for (int q = 0; q < 8; ++q) {
        float4 v = r1[q];
        x1[4 * q + 0] = v.x; x1[4 * q + 1] = v.y; x1[4 * q + 2] = v.z; x1[4 * q + 3] = v.w;
    }
#pragma unroll
    for (int dd = 0; dd < EDGE_DIM; ++dd) {
        x0[32 + dd] = e_feats[(size_t)e0 * (EDGE_DIM * T_STEPS) + dd * T_STEPS + t];
        x1[32 + dd] = e_feats[(size_t)e1 * (EDGE_DIM * T_STEPS) + dd * T_STEPS + t];
    }

    float a0[H], a1[H];
#pragma unroll
    for (int j = 0; j < H; ++j) { a0[j] = 0.f; a1[j] = 0.f; }
#pragma unroll
    for (int k = 0; k < 36; ++k) {
        float xk0 = x0[k], xk1 = x1[k];
#pragma unroll
        for (int j = 0; j < H; j += 4) {
            float4 w = *(const float4*)&W[k * H + j];
            a0[j + 0] += xk0 * w.x; a0[j + 1] += xk0 * w.y; a0[j + 2] += xk0 * w.z; a0[j + 3] += xk0 * w.w;
            a1[j + 0] += xk1 * w.x; a1[j + 1] += xk1 * w.y; a1[j + 2] += xk1 * w.z; a1[j + 3] += xk1 * w.w;
        }
    }
    float4* m0 = (float4*)(m + (size_t)p0 * H);
    float4* m1 = (float4*)(m + (size_t)p1 * H);
#pragma unroll
    for (int q = 0; q < 8; ++q) {
        float4 v;
        v.x = fmaxf(a0[4 * q + 0], 0.f); v.y = fmaxf(a0[4 * q + 1], 0.f);
        v.z = fmaxf(a0[4 * q + 2], 0.f); v.w = fmaxf(a0[4 * q + 3], 0.f);
        m0[q] = v;
        v.x = fmaxf(a1[4 * q + 0], 0.f); v.y = fmaxf(a1[4 * q + 1], 0.f);
        v.z = fmaxf(a1[4 * q + 2], 0.f); v.w = fmaxf(a1[4 * q + 3], 0.f);
        m1[q] = v;
    }
}

// ---------------- node update: gather m rows, h_new = relu([h; agg; rain] @ W_n), fused rain out ----------------
__global__ __launch_bounds__(64) void node_sorted_kernel(const float* __restrict__ h,
                                                         const float* __restrict__ m,
                                                         const int* __restrict__ row_ptr,
                                                         const float* __restrict__ rain0,
                                                         const float* __restrict__ Wn,
                                                         const float* __restrict__ Wrain,
                                                         float* __restrict__ hnew,
                                                         float* __restrict__ out, int t, int last) {
    __shared__ float W[65 * H];
    __shared__ float Wr[H];
    for (int i = threadIdx.x; i < 65 * H; i += 64) W[i] = Wn[i];
    if (threadIdx.x < H) Wr[threadIdx.x] = Wrain[threadIdx.x];
    __syncthreads();
    int n = blockIdx.x * 64 + threadIdx.x;
    if (n >= NN) return;

    float x[65];
    const float4* hr = (const float4*)(h + (size_t)n * H);
#pragma unroll
    for (int q = 0; q < 8; ++q) {
        float4 v = hr[q];
        x[4 * q + 0] = v.x; x[4 * q + 1] = v.y; x[4 * q + 2] = v.z; x[4 * q + 3] = v.w;
    }

    float4 ag[8];
#pragma unroll
    for (int q = 0; q < 8; ++q) ag[q] = make_float4(0.f, 0.f, 0.f, 0.f);
    int rb = row_ptr[n], re = row_ptr[n + 1];
    for (int p = rb; p < re; ++p) {
        const float4* mr = (const float4*)(m + (size_t)p * H);
#pragma unroll
        for (int q = 0; q < 8; ++q) {
            float4 v = mr[q];
            ag[q].x += v.x; ag[q].y += v.y; ag[q].z += v.z; ag[q].w += v.w;
        }
    }
#pragma unroll
    for (int q = 0; q < 8; ++q) {
        x[32 + 4 * q + 0] = ag[q].x; x[32 + 4 * q + 1] = ag[q].y;
        x[32 + 4 * q + 2] = ag[q].z; x[32 + 4 * q + 3] = ag[q].w;
    }
    x[64] = rain0[n * T_STEPS + t];

    float acc[H];
#pragma unroll
    for (int j = 0; j < H; ++j) acc[j] = 0.f;
#pragma unroll
    for (int k = 0; k < 65; ++k) {
        float xk = x[k];
#pragma unroll
        for (int j = 0; j < H; j += 4) {
            float4 w = *(const float4*)&W[k * H + j];
            acc[j + 0] += xk * w.x; acc[j + 1] += xk * w.y;
            acc[j + 2] += xk * w.z; acc[j + 3] += xk * w.w;
        }
    }

    float r = 0.f;
    float4* hw = (float4*)(hnew + (size_t)n * H);
#pragma unroll
    for (int q = 0; q < 8; ++q) {
        float4 v;
        v.x = fmaxf(acc[4 * q + 0], 0.f);
        v.y = fmaxf(acc[4 * q + 1], 0.f);
        v.z = fmaxf(acc[4 * q + 2], 0.f);
        v.w = fmaxf(acc[4 * q + 3], 0.f);
        hw[q] = v;
        r += v.x * Wr[4 * q + 0] + v.y * Wr[4 * q + 1] + v.z * Wr[4 * q + 2] + v.w * Wr[4 * q + 3];
    }
    if (last) out[n * T_STEPS + t] = r;
}

// ---------------- fallback (round-0 atomic path, used only if ws too small) ----------------
__global__ __launch_bounds__(256) void edge_kernel(const float* __restrict__ h,
                                                   const float* __restrict__ e_feats,
                                                   const int* __restrict__ src,
                                                   const int* __restrict__ dst,
                                                   const float* __restrict__ We,
                                                   float* __restrict__ agg, int t) {
    __shared__ float W[36 * H];
    for (int i = threadIdx.x; i < 36 * H; i += 256) W[i] = We[i];
    __syncthreads();
    int e = blockIdx.x * 256 + threadIdx.x;
    if (e >= NE) return;
    int s = src[e], d = dst[e];
    float x[36];
    const float4* hrow = (const float4*)(h + s * H);
#pragma unroll
    for (int q = 0; q < 8; ++q) {
        float4 v = hrow[q];
        x[4 * q + 0] = v.x; x[4 * q + 1] = v.y; x[4 * q + 2] = v.z; x[4 * q + 3] = v.w;
    }
#pragma unroll
    for (int dd = 0; dd < EDGE_DIM; ++dd) x[32 + dd] = e_feats[e * (EDGE_DIM * T_STEPS) + dd * T_STEPS + t];
    float acc[H];
#pragma unroll
    for (int j = 0; j < H; ++j) acc[j] = 0.f;
#pragma unroll
    for (int k = 0; k < 36; ++k) {
        float xk = x[k];
#pragma unroll
        for (int j = 0; j < H; j += 4) {
            float4 w = *(const float4*)&W[k * H + j];
            acc[j + 0] += xk * w.x; acc[j + 1] += xk * w.y;
            acc[j + 2] += xk * w.z; acc[j + 3] += xk * w.w;
        }
    }
    float* ar = agg + (long)d * H;
#pragma unroll
    for (int j = 0; j < H; ++j) atomicAdd(ar + j, fmaxf(acc[j], 0.f));
}

__global__ __launch_bounds__(256) void node_kernel(const float* __restrict__ h,
                                                   const float* __restrict__ agg,
                                                   const float* __restrict__ rain0,
                                                   const float* __restrict__ Wn,
                                                   const float* __restrict__ Wrain,
                                                   float* __restrict__ hnew,
                                                   float* __restrict__ out, int t, int last) {
    __shared__ float W[65 * H];
    __shared__ float Wr[H];
    for (int i = threadIdx.x; i < 65 * H; i += 256) W[i] = Wn[i];
    if (threadIdx.x < H) Wr[threadIdx.x] = Wrain[threadIdx.x];
    __syncthreads();
    int n = blockIdx.x * 256 + threadIdx.x;
    if (n >= NN) return;
    float x[65];
    const float4* hr = (const float4*)(h + n * H);
    const float4* ar = (const float4*)(agg + n * H);
#pragma unroll
    for (int q = 0; q < 8; ++q) {
        float4 v = hr[q];
        x[4 * q + 0] = v.x; x[4 * q + 1] = v.y; x[4 * q + 2] = v.z; x[4 * q + 3] = v.w;
    }
#pragma unroll
    for (int q = 0; q < 8; ++q) {
        float4 v = ar[q];
        x[32 + 4 * q + 0] = v.x; x[32 + 4 * q + 1] = v.y; x[32 + 4 * q + 2] = v.z; x[32 + 4 * q + 3] = v.w;
    }
    x[64] = rain0[n * T_STEPS + t];
    float acc[H];
#pragma unroll
    for (int j = 0; j < H; ++j) acc[j] = 0.f;
#pragma unroll
    for (int k = 0; k < 65; ++k) {
        float xk = x[k];
#pragma unroll
        for (int j = 0; j < H; j += 4) {
            float4 w = *(const float4*)&W[k * H + j];
            acc[j + 0] += xk * w.x; acc[j + 1] += xk * w.y;
            acc[j + 2] += xk * w.z; acc[j + 3] += xk * w.w;
        }
    }
    float r = 0.f;
    float4* hw = (float4*)(hnew + n * H);
#pragma unroll
    for (int q = 0; q < 8; ++q) {
        float4 v;
        v.x = fmaxf(acc[4 * q + 0], 0.f);
        v.y = fmaxf(acc[4 * q + 1], 0.f);
        v.z = fmaxf(acc[4 * q + 2], 0.f);
        v.w = fmaxf(acc[4 * q + 3], 0.f);
        hw[q] = v;
        r += v.x * Wr[4 * q + 0] + v.y * Wr[4 * q + 1] + v.z * Wr[4 * q + 2] + v.w * Wr[4 * q + 3];
    }
    if (last) out[n * T_STEPS + t] = r;
}

extern "C" void kernel_launch(void* const* d_in, const int* in_sizes, int n_in,
                              void* d_out, int out_size, void* d_ws, size_t ws_size,
                              hipStream_t stream) {
    const float* inputs     = (const float*)d_in[0];
    const float* e_feats    = (const float*)d_in[1];
    const float* rain0      = (const float*)d_in[2];
    const float* W_emb      = (const float*)d_in[3];
    const float* W_edge_in  = (const float*)d_in[4];
    const float* W_node_in  = (const float*)d_in[5];
    const float* W_edge_out = (const float*)d_in[6];
    const float* W_node_out = (const float*)d_in[7];
    const float* W_rain     = (const float*)d_in[8];
    const int*   src        = (const int*)d_in[9];
    const int*   dst        = (const int*)d_in[10];
    float* out = (float*)d_out;

    // workspace layout
    size_t fH = (size_t)NN * H;                 // 1.6M floats
    size_t fM = (size_t)NE * H;                 // 25.6M floats
    float* h_a = (float*)d_ws;
    float* h_b = h_a + fH;
    float* m   = h_b + fH;
    int* row_ptr    = (int*)(m + fM);           // NN+1
    int* deg        = row_ptr + (NN + 1);       // NN
    int* cnt        = deg + NN;                 // NN
    int* src_sorted = cnt + NN;                 // NE
    int* eid_sorted = src_sorted + NE;          // NE
    size_t needed = ((fH * 2 + fM) + (size_t)(NN + 1 + NN + NN + NE + NE)) * 4;

    if (ws_size >= needed) {
        embed_kernel<<<(NN * H + 255) / 256, 256, 0, stream>>>(inputs, W_emb, h_a);

        // CSR build (per call; deterministic work)
        hipMemsetAsync(deg, 0, (size_t)2 * NN * sizeof(int), stream);  // deg + cnt contiguous
        hist_kernel<<<(NE + 255) / 256, 256, 0, stream>>>(dst, deg);
        scan_kernel<<<1, 1024, 0, stream>>>(deg, row_ptr);
        scatter_kernel<<<(NE + 255) / 256, 256, 0, stream>>>(src, dst, row_ptr, cnt, src_sorted, eid_sorted);

        float* hc = h_a;
        float* hn = h_b;
        for (int t = 0; t < T_STEPS; ++t) {
            for (int s = 0; s < 3; ++s) {
                const float* We = (s < 2) ? (W_edge_in + (size_t)s * 36 * H) : W_edge_out;
                const float* Wn = (s < 2) ? (W_node_in + (size_t)s * 65 * H) : W_node_out;
                edge_sorted_kernel<<<(HALF_E + 255) / 256, 256, 0, stream>>>(hc, e_feats, src_sorted, eid_sorted, We, m, t);
                node_sorted_kernel<<<(NN + 63) / 64, 64, 0, stream>>>(hc, m, row_ptr, rain0, Wn, W_rain, hn, out, t, (s == 2) ? 1 : 0);
                float* tmp = hc; hc = hn; hn = tmp;
            }
        }
    } else {
        // fallback: atomic path (round-0), needs 3*NN*H floats
        float* agg = m;  // reuse slot
        embed_kernel<<<(NN * H + 255) / 256, 256, 0, stream>>>(inputs, W_emb, h_a);
        float* hc = h_a;
        float* hn = h_b;
        for (int t = 0; t < T_STEPS; ++t) {
            for (int s = 0; s < 3; ++s) {
                const float* We = (s < 2) ? (W_edge_in + (size_t)s * 36 * H) : W_edge_out;
                const float* Wn = (s < 2) ? (W_node_in + (size_t)s * 65 * H) : W_node_out;
                hipMemsetAsync(agg, 0, (size_t)NN * H * sizeof(float), stream);
                edge_kernel<<<(NE + 255) / 256, 256, 0, stream>>>(hc, e_feats, src, dst, We, agg, t);
                node_kernel<<<(NN + 255) / 256, 256, 0, stream>>>(hc, agg, rain0, Wn, W_rain, hn, out, t, (s == 2) ? 1 : 0);
                float* tmp = hc; hc = hn; hn = tmp;
            }
        }
    }
}

// Round 3
// 1600.346 us; speedup vs baseline: 10.1074x; 1.0371x over previous
//
#include <hip/hip_runtime.h>

#define NN 50000
#define NE 800000
#define IN_DIM 16
#define H 32
#define EDGE_DIM 4
#define T_STEPS 4
#define NPB 16              // nodes per block (50000 / 16 = 3125 exact)
#define NBLK (NN / NPB)

// ---------------- embedding: h0 = inputs @ W_emb ----------------
__global__ __launch_bounds__(256) void embed_kernel(const float* __restrict__ inputs,
                                                    const float* __restrict__ W_emb,
                                                    float* __restrict__ h) {
    __shared__ float W[IN_DIM * H];
    for (int i = threadIdx.x; i < IN_DIM * H; i += 256) W[i] = W_emb[i];
    __syncthreads();
    int idx = blockIdx.x * 256 + threadIdx.x;
    if (idx >= NN * H) return;
    int n = idx >> 5, j = idx & 31;
    const float* xr = inputs + n * IN_DIM;
    float acc = 0.f;
#pragma unroll
    for (int k = 0; k < IN_DIM; ++k) acc += xr[k] * W[k * H + j];
    h[idx] = acc;
}

// ---------------- CSR build ----------------
__global__ __launch_bounds__(256) void hist_kernel(const int* __restrict__ dst, int* __restrict__ deg) {
    int e = blockIdx.x * 256 + threadIdx.x;
    if (e < NE) atomicAdd(&deg[dst[e]], 1);
}

#define SCAN_CHUNK 49
__global__ __launch_bounds__(1024) void scan_kernel(const int* __restrict__ deg, int* __restrict__ row_ptr) {
    __shared__ int part[1024];
    int tid = threadIdx.x;
    int start = tid * SCAN_CHUNK;
    int s = 0;
    for (int i = 0; i < SCAN_CHUNK; ++i) {
        int idx = start + i;
        if (idx < NN) s += deg[idx];
    }
    part[tid] = s;
    __syncthreads();
    for (int off = 1; off < 1024; off <<= 1) {
        int v = (tid >= off) ? part[tid - off] : 0;
        __syncthreads();
        part[tid] += v;
        __syncthreads();
    }
    int run = (tid == 0) ? 0 : part[tid - 1];
    for (int i = 0; i < SCAN_CHUNK; ++i) {
        int idx = start + i;
        if (idx <= NN) row_ptr[idx] = run;
        if (idx < NN) run += deg[idx];
    }
}

__global__ __launch_bounds__(256) void scatter_kernel(const int* __restrict__ src, const int* __restrict__ dst,
                                                      const int* __restrict__ row_ptr, int* __restrict__ cnt,
                                                      int* __restrict__ src_sorted, int* __restrict__ eid_sorted) {
    int e = blockIdx.x * 256 + threadIdx.x;
    if (e >= NE) return;
    int d = dst[e];
    int pos = row_ptr[d] + atomicAdd(&cnt[d], 1);
    src_sorted[pos] = src[e];
    eid_sorted[pos] = e;
}

// ---------------- ef re-layout: ef_sorted[t][p][4] coalesced per layer ----------------
__global__ __launch_bounds__(256) void ef_sort_kernel(const float* __restrict__ e_feats,
                                                      const int* __restrict__ eid_sorted,
                                                      float* __restrict__ ef_sorted) {
    int p = blockIdx.x * 256 + threadIdx.x;
    if (p >= NE) return;
    int e = eid_sorted[p];
    float buf[16];
    const float4* srcp = (const float4*)(e_feats + (size_t)e * (EDGE_DIM * T_STEPS));
#pragma unroll
    for (int q = 0; q < 4; ++q) {
        float4 v = srcp[q];
        buf[4 * q + 0] = v.x; buf[4 * q + 1] = v.y; buf[4 * q + 2] = v.z; buf[4 * q + 3] = v.w;
    }
#pragma unroll
    for (int t = 0; t < T_STEPS; ++t) {
        float4 o = make_float4(buf[t], buf[4 + t], buf[8 + t], buf[12 + t]);
        *(float4*)(ef_sorted + ((size_t)t * NE + p) * 4) = o;
    }
}

// ---------------- fused layer: edge msgs -> LDS segsum -> node update -> (rain) ----------------
__global__ __launch_bounds__(256) void layer_kernel(const float* __restrict__ h,
                                                    const float* __restrict__ ef_t,     // t-plane base
                                                    const int* __restrict__ src_sorted,
                                                    const int* __restrict__ row_ptr,
                                                    const float* __restrict__ rain0,
                                                    const float* __restrict__ We,
                                                    const float* __restrict__ Wn,
                                                    const float* __restrict__ Wrain,
                                                    float* __restrict__ hnew,
                                                    float* __restrict__ out,
                                                    int t, int last) {
    __shared__ float sWe[36 * 32];        // [k][c] row-major (broadcast reads)
    __shared__ float sWnT[32 * 68];       // transposed [c][k], pad 68 (16B aligned rows)
    __shared__ float sWr[32];
    __shared__ float msgT[32 * 257];      // [c][r] pad 257 (conflict-free col writes / row reads)
    __shared__ float sagg[16 * 36];       // [g][c] pad 36 (16B aligned)
    __shared__ float shl[16 * 36];        // staged h rows of own nodes
    __shared__ int srp[NPB + 1];

    int tid = threadIdx.x;
    int nb0 = blockIdx.x * NPB;

    for (int i = tid; i < 36 * 32; i += 256) sWe[i] = We[i];
    for (int i = tid; i < 65 * 32; i += 256) { int k = i >> 5, c = i & 31; sWnT[c * 68 + k] = Wn[i]; }
    if (tid < 32) sWr[tid] = Wrain[tid];
    if (tid <= NPB) srp[tid] = row_ptr[nb0 + tid];
    for (int i = tid; i < 16 * 36; i += 256) sagg[i] = 0.f;
    __syncthreads();

    int e0 = srp[0], e1 = srp[NPB];

    for (int cb = e0; cb < e1; cb += 256) {
        int p = cb + tid;
        if (p < e1) {
            int s = src_sorted[p];
            float x[36];
            const float4* hr = (const float4*)(h + (size_t)s * H);
#pragma unroll
            for (int q = 0; q < 8; ++q) {
                float4 v = hr[q];
                x[4 * q + 0] = v.x; x[4 * q + 1] = v.y; x[4 * q + 2] = v.z; x[4 * q + 3] = v.w;
            }
            float4 ev = *(const float4*)(ef_t + (size_t)p * 4);
            x[32] = ev.x; x[33] = ev.y; x[34] = ev.z; x[35] = ev.w;

            float acc[32];
#pragma unroll
            for (int j = 0; j < 32; ++j) acc[j] = 0.f;
#pragma unroll
            for (int k = 0; k < 36; ++k) {
                float xk = x[k];
#pragma unroll
                for (int j = 0; j < 32; j += 4) {
                    float4 w = *(const float4*)&sWe[k * 32 + j];
                    acc[j + 0] += xk * w.x; acc[j + 1] += xk * w.y;
                    acc[j + 2] += xk * w.z; acc[j + 3] += xk * w.w;
                }
            }
#pragma unroll
            for (int c = 0; c < 32; ++c) msgT[c * 257 + tid] = fmaxf(acc[c], 0.f);
        }
        __syncthreads();
        {
            int g = tid >> 4, cc = tid & 15;
            int lo = max(srp[g], cb), hi = min(srp[g + 1], cb + 256);
            float s0 = 0.f, s1 = 0.f;
            for (int r = lo - cb; r < hi - cb; ++r) {
                s0 += msgT[cc * 257 + r];
                s1 += msgT[(cc + 16) * 257 + r];
            }
            sagg[g * 36 + cc] += s0;
            sagg[g * 36 + cc + 16] += s1;
        }
        __syncthreads();
    }

    // stage own nodes' h rows
    for (int i = tid; i < NPB * 32; i += 256) {
        int g = i >> 5, c = i & 31;
        shl[g * 36 + c] = h[(size_t)(nb0 + g) * H + c];
    }
    __syncthreads();

    int c = tid & 31;
#pragma unroll
    for (int pass = 0; pass < 2; ++pass) {
        int g = (tid >> 5) + pass * 8;
        float acc = 0.f;
#pragma unroll
        for (int q = 0; q < 8; ++q) {
            float4 xv = *(const float4*)&shl[g * 36 + 4 * q];
            float4 wv = *(const float4*)&sWnT[c * 68 + 4 * q];
            acc += xv.x * wv.x + xv.y * wv.y + xv.z * wv.z + xv.w * wv.w;
        }
#pragma unroll
        for (int q = 0; q < 8; ++q) {
            float4 xv = *(const float4*)&sagg[g * 36 + 4 * q];
            float4 wv = *(const float4*)&sWnT[c * 68 + 32 + 4 * q];
            acc += xv.x * wv.x + xv.y * wv.y + xv.z * wv.z + xv.w * wv.w;
        }
        float rain = rain0[(size_t)(nb0 + g) * T_STEPS + t];
        acc += rain * sWnT[c * 68 + 64];
        float v = fmaxf(acc, 0.f);
        hnew[(size_t)(nb0 + g) * H + c] = v;
        if (last) {
            float rv = v * sWr[c];
#pragma unroll
            for (int off = 16; off >= 1; off >>= 1) rv += __shfl_xor(rv, off, 64);
            if ((tid & 31) == 0) out[(size_t)(nb0 + g) * T_STEPS + t] = rv;
        }
    }
}

extern "C" void kernel_launch(void* const* d_in, const int* in_sizes, int n_in,
                              void* d_out, int out_size, void* d_ws, size_t ws_size,
                              hipStream_t stream) {
    const float* inputs     = (const float*)d_in[0];
    const float* e_feats    = (const float*)d_in[1];
    const float* rain0      = (const float*)d_in[2];
    const float* W_emb      = (const float*)d_in[3];
    const float* W_edge_in  = (const float*)d_in[4];
    const float* W_node_in  = (const float*)d_in[5];
    const float* W_edge_out = (const float*)d_in[6];
    const float* W_node_out = (const float*)d_in[7];
    const float* W_rain     = (const float*)d_in[8];
    const int*   src        = (const int*)d_in[9];
    const int*   dst        = (const int*)d_in[10];
    float* out = (float*)d_out;

    // workspace layout (~71 MB; prior rounds granted >= 122 MB)
    size_t fH = (size_t)NN * H;                     // 1.6M floats
    size_t fE = (size_t)NE * 4;                     // 3.2M floats per t-plane
    float* h_a       = (float*)d_ws;
    float* h_b       = h_a + fH;
    float* ef_sorted = h_b + fH;                    // T * NE * 4 floats
    int* row_ptr     = (int*)(ef_sorted + (size_t)T_STEPS * fE);  // NN+1
    int* deg         = row_ptr + (NN + 1);          // NN
    int* cnt         = deg + NN;                    // NN
    int* src_sorted  = cnt + NN;                    // NE
    int* eid_sorted  = src_sorted + NE;             // NE

    embed_kernel<<<(NN * H + 255) / 256, 256, 0, stream>>>(inputs, W_emb, h_a);

    // CSR build
    hipMemsetAsync(deg, 0, (size_t)2 * NN * sizeof(int), stream);  // deg + cnt contiguous
    hist_kernel<<<(NE + 255) / 256, 256, 0, stream>>>(dst, deg);
    scan_kernel<<<1, 1024, 0, stream>>>(deg, row_ptr);
    scatter_kernel<<<(NE + 255) / 256, 256, 0, stream>>>(src, dst, row_ptr, cnt, src_sorted, eid_sorted);
    ef_sort_kernel<<<(NE + 255) / 256, 256, 0, stream>>>(e_feats, eid_sorted, ef_sorted);

    float* hc = h_a;
    float* hn = h_b;
    for (int t = 0; t < T_STEPS; ++t) {
        const float* ef_t = ef_sorted + (size_t)t * fE;
        for (int s = 0; s < 3; ++s) {
            const float* We = (s < 2) ? (W_edge_in + (size_t)s * 36 * H) : W_edge_out;
            const float* Wn = (s < 2) ? (W_node_in + (size_t)s * 65 * H) : W_node_out;
            layer_kernel<<<NBLK, 256, 0, stream>>>(hc, ef_t, src_sorted, row_ptr, rain0,
                                                   We, Wn, W_rain, hn, out, t, (s == 2) ? 1 : 0);
            float* tmp = hc; hc = hn; hn = tmp;
        }
    }
}